// Round 12
// baseline (4993.905 us; speedup 1.0000x reference)
//
#include <hip/hip_runtime.h>

typedef __attribute__((ext_vector_type(8))) short short8;
typedef __attribute__((ext_vector_type(4))) float f32x4;

#define DEV static __device__ __forceinline__

DEV unsigned short f2b(float f) {
    union { float f; unsigned u; } v; v.f = f;
    unsigned r = (v.u + 0x7FFFu + ((v.u >> 16) & 1u)) >> 16;
    return (unsigned short)r;
}
DEV float b2f(unsigned short s) {
    union { unsigned u; float f; } v; v.u = ((unsigned)s) << 16;
    return v.f;
}
DEV float sigm(float x) { return 1.0f / (1.0f + __expf(-x)); }

DEV unsigned long long ald(const unsigned long long* p) {
    return __hip_atomic_load(p, __ATOMIC_RELAXED, __HIP_MEMORY_SCOPE_AGENT);
}
DEV unsigned aldu(const unsigned* p) {
    return __hip_atomic_load(p, __ATOMIC_RELAXED, __HIP_MEMORY_SCOPE_AGENT);
}

// ---------------- converts ----------------

__global__ void k_f2b(const float* __restrict__ src, unsigned short* __restrict__ dst, int n4) {
    int i = blockIdx.x * blockDim.x + threadIdx.x;
    if (i < n4) {
        float4 v = ((const float4*)src)[i];
        ushort4 o;
        o.x = f2b(v.x); o.y = f2b(v.y); o.z = f2b(v.z); o.w = f2b(v.w);
        ((ushort4*)dst)[i] = o;
    }
}

// dst[(4j+g)][k] = bf16(src[(g*1024+j)][k]); Kq = K/4
__global__ void k_perm(const float* __restrict__ src, unsigned short* __restrict__ dst, int Kq) {
    int i = blockIdx.x * blockDim.x + threadIdx.x;
    int total = 4096 * Kq;
    if (i >= total) return;
    int rp = i / Kq, kq = i - rp * Kq;
    int j = rp >> 2, g = rp & 3;
    float4 v = ((const float4*)src)[(size_t)(g * 1024 + j) * Kq + kq];
    ushort4 o;
    o.x = f2b(v.x); o.y = f2b(v.y); o.z = f2b(v.z); o.w = f2b(v.w);
    ((ushort4*)dst)[(size_t)rp * Kq + kq] = o;
}

__global__ void k_bias(const float* __restrict__ bi0, const float* __restrict__ bh0,
                       const float* __restrict__ bi1, const float* __restrict__ bh1,
                       float* __restrict__ d0, float* __restrict__ d1) {
    int i = blockIdx.x * blockDim.x + threadIdx.x;
    if (i < 4096) {
        int j = i >> 2, g = i & 3, s = g * 1024 + j;
        d0[i] = bi0[s] + bh0[s];
        d1[i] = bi1[s] + bh1[s];
    }
}

// writes initial h (packed 2xbf16) into parity-1 buffers; c as fp32
__global__ void k_init(const float* __restrict__ hx, const float* __restrict__ cx,
                       unsigned* __restrict__ hB0, unsigned* __restrict__ hB1,
                       float* __restrict__ c0, float* __restrict__ c1) {
    int i = blockIdx.x * blockDim.x + threadIdx.x;
    if (i < 128 * 512) {
        int b = i >> 9, j = i & 511;
        const float* p0 = hx + (size_t)b * 1024 + j * 2;
        const float* p1 = hx + 131072 + (size_t)b * 1024 + j * 2;
        hB0[i] = (unsigned)f2b(p0[0]) | ((unsigned)f2b(p0[1]) << 16);
        hB1[i] = (unsigned)f2b(p1[0]) | ((unsigned)f2b(p1[1]) << 16);
        c0[i * 2] = cx[i * 2];
        c0[i * 2 + 1] = cx[i * 2 + 1];
        c1[i * 2] = cx[131072 + i * 2];
        c1[i * 2 + 1] = cx[131072 + i * 2 + 1];
    }
}

// ---------------- xg GEMM (layer 0 input projection) ----------------
__global__ __launch_bounds__(256) void k_gemm(
    const unsigned short* __restrict__ A, const unsigned short* __restrict__ W,
    unsigned short* __restrict__ out, int K, int t0, int TC) {
    __shared__ unsigned short ldsA[128 * 40];
    __shared__ unsigned short ldsB[128 * 40];
    const int tid = threadIdx.x;
    const int w = tid >> 6, l = tid & 63;
    const int wm = w >> 1, wn = w & 1;
    const int bm = blockIdx.x, bn = blockIdx.y;
    const int lr = l & 15, lk = (l >> 4) * 8;

    const int row0 = tid >> 2, inb = (tid & 3) << 4;
    const int row1 = row0 + 64;
    const int v0 = bm * 128 + row0, v1 = bm * 128 + row1;
    const size_t ar0 = (size_t)((v0 / TC) * 256 + t0 + (v0 % TC));
    const size_t ar1 = (size_t)((v1 / TC) * 256 + t0 + (v1 % TC));
    const size_t br0 = (size_t)(bn * 128 + row0);
    const size_t br1 = (size_t)(bn * 128 + row1);

    f32x4 acc[4][4];
#pragma unroll
    for (int a = 0; a < 4; a++)
#pragma unroll
        for (int b = 0; b < 4; b++) acc[a][b] = (f32x4){0.f, 0.f, 0.f, 0.f};

    for (int ks = 0; ks < K; ks += 32) {
        uint4 a0 = *(const uint4*)((const char*)A + (ar0 * K + ks) * 2 + inb);
        uint4 a1 = *(const uint4*)((const char*)A + (ar1 * K + ks) * 2 + inb);
        uint4 b0 = *(const uint4*)((const char*)W + (br0 * K + ks) * 2 + inb);
        uint4 b1 = *(const uint4*)((const char*)W + (br1 * K + ks) * 2 + inb);
        *(uint4*)((char*)ldsA + row0 * 80 + inb) = a0;
        *(uint4*)((char*)ldsA + row1 * 80 + inb) = a1;
        *(uint4*)((char*)ldsB + row0 * 80 + inb) = b0;
        *(uint4*)((char*)ldsB + row1 * 80 + inb) = b1;
        __syncthreads();
        short8 af[4], bf[4];
#pragma unroll
        for (int mt = 0; mt < 4; mt++)
            af[mt] = *(const short8*)((const char*)ldsA + (wm * 64 + mt * 16 + lr) * 80 + lk * 2);
#pragma unroll
        for (int nt = 0; nt < 4; nt++)
            bf[nt] = *(const short8*)((const char*)ldsB + (wn * 64 + nt * 16 + lr) * 80 + lk * 2);
#pragma unroll
        for (int mt = 0; mt < 4; mt++)
#pragma unroll
            for (int nt = 0; nt < 4; nt++)
                acc[mt][nt] = __builtin_amdgcn_mfma_f32_16x16x32_bf16(af[mt], bf[nt], acc[mt][nt], 0, 0, 0);
        __syncthreads();
    }

#pragma unroll
    for (int mt = 0; mt < 4; mt++)
#pragma unroll
        for (int nt = 0; nt < 4; nt++)
#pragma unroll
            for (int v4 = 0; v4 < 4; v4++) {
                int vr = bm * 128 + wm * 64 + mt * 16 + (l >> 4) * 4 + v4;
                int col = bn * 128 + wn * 64 + nt * 16 + lr;
                out[(size_t)vr * 4096 + col] = f2b(acc[mt][nt][v4]);
            }
}

// ---------------- fused 2-layer pipelined recurrent kernel ----------------
// 256 wgs (1/CU), 512 threads (8 waves), cooperative. wgid<128: LAYER 0;
// wgid>=128: LAYER 1 (runs tick t concurrently with L0 tick t+1 on other CUs).
//
// L0 wg: 4 groups(32 rows) x 32 col-wgs(128 gate cols). W_hh0: gate-rows 0..47 in
//   LDS (pitch 2064B), rows 48..127 in regs (wreg[20]/wave, 8-way K-split of 1024).
//   64 MFMA/wave/tick; 3-stage split-K reduce; epilogue 512 thr x 2 cells (+xg).
// L1 wg: 2 groups(64 rows) x 64 col-wgs(64 gate cols). Virtual K=2048: waves 0-3
//   consume h0(t) vs W_ih1 (k-quarter each), waves 4-7 consume h1(t-1) vs W_hh1.
//   LDS: ih rows 0..31 + hh rows 0..15; regs: ih 32..63 (w<4), hh 16..63 (w>=4).
//   128 MFMA/wave/tick; same reduce; epilogue 512 thr x 2 cells (no xg); writes out.
//
// Flags (64B stride, absolute tag t+1, drain-then-signal — r10-proven):
//   [0..127]   L0: g*32+nb.  [128..255] L1: g*64+n.
//   L0 tick t polls: own-group L0 flags >= t  AND  overlapping L1 flags >= t-1
//     (depth-2 anti-dep: L1 read h0(t-2) during its tick t-2 -> flag t-1).
//   L1 tick t polls: overlapping L0 flags >= t+1 (h0(t) ready) AND own L1 >= t.
// h parity: write h(t) to (t&1 ? B : A)... stored as hX with write=(t&1)?hB:hA,
// read h(t-1)=(t&1)?hA:hB (r4 convention); L1 reads h0(t) from (t&1)?h0B:h0A.
__global__ __launch_bounds__(512, 2) void k_fused(
    const unsigned short* __restrict__ Wh0,   // W_hh0 perm [4096][1024]
    const unsigned short* __restrict__ Wi1,   // W_ih1 perm [4096][1024]
    const unsigned short* __restrict__ Wh1,   // W_hh1 perm [4096][1024]
    const unsigned short* __restrict__ xg,    // [B][TC][4096] layer0 input proj
    const float* __restrict__ bias0,
    const float* __restrict__ bias1,
    float* __restrict__ c0buf, float* __restrict__ c1buf,
    unsigned* __restrict__ h0A, unsigned* __restrict__ h0B,
    unsigned* __restrict__ h1A, unsigned* __restrict__ h1B,
    float* __restrict__ out,
    unsigned* __restrict__ flags,
    int t0, int TC)
{
    extern __shared__ char smem[];
    char* ldsW = smem;                       // 48 rows x 2064B
    float* P0 = (float*)(smem + 48 * 2064);  // L0: [32][132]; L1: [64][68]
    const int wgid = (int)blockIdx.x;
    const int tid = threadIdx.x;
    const int wv = tid >> 6;
    const int l = tid & 63;
    const int lr = l & 15, lq = l >> 4;

    if (wgid < 128) {
        // ================= LAYER 0 =================
        const int g = wgid >> 5;     // rows g*32..+32
        const int nb = wgid & 31;    // gate cols nb*128..+128
        float* P1 = P0 + 32 * 132;
        float* P2 = P1 + 32 * 132;

        // LDS W: gate-rows nb*128..+48
        {
            const char* src = (const char*)(Wh0 + (size_t)nb * 128 * 1024);
#pragma unroll
            for (int it = 0; it < 12; it++) {
                int idx = it * 512 + tid;
                int row = idx >> 7, inr = (idx & 127) << 4;
                *(uint4*)(ldsW + row * 2064 + inr) = *(const uint4*)(src + (size_t)row * 2048 + inr);
            }
        }
        // reg W: gate-rows 48..127 (5 tiles), this wave's K-eighth
        short8 wreg[20];
        {
            const unsigned short* src = Wh0 + ((size_t)nb * 128 + 48) * 1024 + wv * 128;
#pragma unroll
            for (int ct = 0; ct < 5; ct++)
#pragma unroll
                for (int kk = 0; kk < 4; kk++)
                    wreg[ct * 4 + kk] =
                        *(const short8*)(src + (size_t)(ct * 16 + lr) * 1024 + kk * 32 + lq * 8);
        }

        const int er = tid >> 4, ep = tid & 15;       // row 0..31, unit-pair
        const int b0 = g * 32 + er;
        const int ec0 = nb * 128 + ep * 8;
        const int eu0 = nb * 32 + ep * 2;
        float2 c2 = *(const float2*)(c0buf + (size_t)b0 * 1024 + eu0);
        const float4 bsA = *(const float4*)(bias0 + ec0);
        const float4 bsB = *(const float4*)(bias0 + ec0 + 4);

        const size_t abase = (size_t)(g * 32 + lr) * 256 + (size_t)wv * 32 + lq * 2;
        const char* wp = ldsW + (size_t)lr * 2064 + wv * 256 + lq * 16;

        const unsigned* fA = flags + (size_t)(g * 32 + (l & 31)) * 16;          // own group (32)
        const unsigned* fB = flags + (size_t)(128 + (g >> 1) * 64 + l) * 16;    // L1 readers (64)
        unsigned* fmine = flags + (size_t)(g * 32 + nb) * 16;

        __syncthreads();

        for (int dt = 0; dt < TC; dt++) {
            const int t = t0 + dt;
            uint4 xv = *(const uint4*)(xg + ((size_t)b0 * TC + dt) * 4096 + ec0);

            if (t > 0) {
                const unsigned tgt = (unsigned)t;
                while (!__all((aldu(fA) >= tgt) & (aldu(fB) >= tgt - 1))) {}
            }

            const unsigned long long* ap =
                (const unsigned long long*)((t & 1) ? h0A : h0B) + abase;
            f32x4 acc[2][8];
#pragma unroll
            for (int i = 0; i < 2; i++)
#pragma unroll
                for (int j = 0; j < 8; j++) acc[i][j] = (f32x4){0.f, 0.f, 0.f, 0.f};
#pragma unroll
            for (int kk = 0; kk < 4; kk++) {
                short8 bl0 = *(const short8*)(wp + 0 * 16 * 2064 + kk * 64);
                short8 bl1 = *(const short8*)(wp + 1 * 16 * 2064 + kk * 64);
                short8 bl2 = *(const short8*)(wp + 2 * 16 * 2064 + kk * 64);
                union AV { unsigned long long u[2]; short8 s; } av0, av1;
                av0.u[0] = ald(ap + kk * 8);
                av0.u[1] = ald(ap + kk * 8 + 1);
                acc[0][0] = __builtin_amdgcn_mfma_f32_16x16x32_bf16(av0.s, bl0, acc[0][0], 0, 0, 0);
                acc[0][1] = __builtin_amdgcn_mfma_f32_16x16x32_bf16(av0.s, bl1, acc[0][1], 0, 0, 0);
                acc[0][2] = __builtin_amdgcn_mfma_f32_16x16x32_bf16(av0.s, bl2, acc[0][2], 0, 0, 0);
#pragma unroll
                for (int ct = 0; ct < 5; ct++)
                    acc[0][3 + ct] = __builtin_amdgcn_mfma_f32_16x16x32_bf16(av0.s, wreg[ct * 4 + kk], acc[0][3 + ct], 0, 0, 0);
                av1.u[0] = ald(ap + 16 * 256 + kk * 8);
                av1.u[1] = ald(ap + 16 * 256 + kk * 8 + 1);
                acc[1][0] = __builtin_amdgcn_mfma_f32_16x16x32_bf16(av1.s, bl0, acc[1][0], 0, 0, 0);
                acc[1][1] = __builtin_amdgcn_mfma_f32_16x16x32_bf16(av1.s, bl1, acc[1][1], 0, 0, 0);
                acc[1][2] = __builtin_amdgcn_mfma_f32_16x16x32_bf16(av1.s, bl2, acc[1][2], 0, 0, 0);
#pragma unroll
                for (int ct = 0; ct < 5; ct++)
                    acc[1][3 + ct] = __builtin_amdgcn_mfma_f32_16x16x32_bf16(av1.s, wreg[ct * 4 + kk], acc[1][3 + ct], 0, 0, 0);
            }

            // 3-stage reduce of 8 partials
            if (wv >= 5) {
                float* P = (wv == 5) ? P0 : (wv == 6) ? P1 : P2;
#pragma unroll
                for (int rt = 0; rt < 2; rt++)
#pragma unroll
                    for (int j = 0; j < 8; j++)
#pragma unroll
                        for (int v = 0; v < 4; v++)
                            P[(rt * 16 + lq * 4 + v) * 132 + j * 16 + lr] = acc[rt][j][v];
            }
            __syncthreads();
            if (wv >= 2 && wv <= 4) {
                float* P = (wv == 2) ? P0 : (wv == 3) ? P1 : P2;
#pragma unroll
                for (int rt = 0; rt < 2; rt++)
#pragma unroll
                    for (int j = 0; j < 8; j++)
#pragma unroll
                        for (int v = 0; v < 4; v++)
                            P[(rt * 16 + lq * 4 + v) * 132 + j * 16 + lr] += acc[rt][j][v];
            }
            __syncthreads();
            if (wv < 2) {
                float* P = (wv == 0) ? P0 : P1;
#pragma unroll
                for (int rt = 0; rt < 2; rt++)
#pragma unroll
                    for (int j = 0; j < 8; j++)
#pragma unroll
                        for (int v = 0; v < 4; v++)
                            P[(rt * 16 + lq * 4 + v) * 132 + j * 16 + lr] += acc[rt][j][v];
            }
            __syncthreads();

            // epilogue: all 512 threads, 2 cells each
            {
                const float* pa = P0 + er * 132 + ep * 8;
                const float* pb = P1 + er * 132 + ep * 8;
                const float* pc = P2 + er * 132 + ep * 8;
                const unsigned short* xs = (const unsigned short*)&xv;
                float p0 = pa[0] + pb[0] + pc[0] + b2f(xs[0]) + bsA.x;
                float p1 = pa[1] + pb[1] + pc[1] + b2f(xs[1]) + bsA.y;
                float p2 = pa[2] + pb[2] + pc[2] + b2f(xs[2]) + bsA.z;
                float p3 = pa[3] + pb[3] + pc[3] + b2f(xs[3]) + bsA.w;
                float q0 = pa[4] + pb[4] + pc[4] + b2f(xs[4]) + bsB.x;
                float q1 = pa[5] + pb[5] + pc[5] + b2f(xs[5]) + bsB.y;
                float q2 = pa[6] + pb[6] + pc[6] + b2f(xs[6]) + bsB.z;
                float q3 = pa[7] + pb[7] + pc[7] + b2f(xs[7]) + bsB.w;
                float i0 = sigm(p0), f0 = sigm(p1), gv0 = tanhf(p2), o0 = sigm(p3);
                float i1 = sigm(q0), f1 = sigm(q1), gv1 = tanhf(q2), o1 = sigm(q3);
                c2.x = f0 * c2.x + i0 * gv0;
                c2.y = f1 * c2.y + i1 * gv1;
                float h0v = o0 * tanhf(c2.x);
                float h1v = o1 * tanhf(c2.y);
                unsigned hp = (unsigned)f2b(h0v) | ((unsigned)f2b(h1v) << 16);
                unsigned* hout = (t & 1) ? h0B : h0A;
                __hip_atomic_store(hout + (size_t)b0 * 512 + nb * 16 + ep, hp,
                                   __ATOMIC_RELAXED, __HIP_MEMORY_SCOPE_AGENT);
            }
            __syncthreads();   // drain h stores before signal
            if (tid == 0)
                __hip_atomic_store(fmine, (unsigned)(t + 1),
                                   __ATOMIC_RELAXED, __HIP_MEMORY_SCOPE_AGENT);
        }
        *(float2*)(c0buf + (size_t)b0 * 1024 + eu0) = c2;
    } else {
        // ================= LAYER 1 =================
        const int w1 = wgid - 128;
        const int g = w1 >> 6;     // rows g*64..+64
        const int n = w1 & 63;     // gate cols n*64..+64, units n*16..+16
        float* P1 = P0 + 64 * 68;
        float* P2 = P1 + 64 * 68;

        // LDS W: rows 0..31 = W_ih1 gate-rows n*64..+32; rows 32..47 = W_hh1 n*64..+16
        {
#pragma unroll
            for (int it = 0; it < 12; it++) {
                int idx = it * 512 + tid;
                int row = idx >> 7, inr = (idx & 127) << 4;
                const char* src = (row < 32)
                    ? (const char*)(Wi1 + (size_t)(n * 64 + row) * 1024)
                    : (const char*)(Wh1 + (size_t)(n * 64 + row - 32) * 1024);
                *(uint4*)(ldsW + row * 2064 + inr) = *(const uint4*)(src + inr);
            }
        }
        // reg W: wv<4: ih gate-rows 32..63 (2 tiles) x k-quarter wv;
        //        wv>=4: hh gate-rows 16..63 (3 tiles) x k-quarter wv-4
        short8 wreg[24];
        {
            if (wv < 4) {
                const unsigned short* src = Wi1 + ((size_t)n * 64 + 32) * 1024 + wv * 256;
#pragma unroll
                for (int ct = 0; ct < 2; ct++)
#pragma unroll
                    for (int kk = 0; kk < 8; kk++)
                        wreg[ct * 8 + kk] =
                            *(const short8*)(src + (size_t)(ct * 16 + lr) * 1024 + kk * 32 + lq * 8);
            } else {
                const unsigned short* src = Wh1 + ((size_t)n * 64 + 16) * 1024 + (wv - 4) * 256;
#pragma unroll
                for (int ct = 0; ct < 3; ct++)
#pragma unroll
                    for (int kk = 0; kk < 8; kk++)
                        wreg[ct * 8 + kk] =
                            *(const short8*)(src + (size_t)(ct * 16 + lr) * 1024 + kk * 32 + lq * 8);
            }
        }

        const int er2 = tid >> 3, up = tid & 7;   // row 0..63, unit-pair 0..7
        const int b1 = g * 64 + er2;
        const int ec = n * 64 + up * 8;
        const int u0 = n * 16 + up * 2;
        float2 c2 = *(const float2*)(c1buf + (size_t)b1 * 1024 + u0);
        const float4 bsA = *(const float4*)(bias1 + ec);
        const float4 bsB = *(const float4*)(bias1 + ec + 4);

        const size_t abase = (size_t)(g * 64 + lr) * 256 + (size_t)(wv & 3) * 64 + lq * 2;
        const char* wpl = (wv < 4)
            ? (ldsW + (size_t)lr * 2064 + wv * 512 + lq * 16)
            : (ldsW + (size_t)(32 + lr) * 2064 + (wv - 4) * 512 + lq * 16);

        const unsigned* fA = flags + (size_t)(g * 64 + l) * 16;          // L0 producers (64)
        const unsigned* fB = flags + (size_t)(128 + g * 64 + l) * 16;    // own group (64)
        unsigned* fmine = flags + (size_t)(128 + g * 64 + n) * 16;

        __syncthreads();

        for (int dt = 0; dt < TC; dt++) {
            const int t = t0 + dt;

            {
                const unsigned tgt = (unsigned)t;
                while (!__all((aldu(fA) >= tgt + 1) & (aldu(fB) >= tgt))) {}
            }

            const unsigned long long* ap = (wv < 4)
                ? ((const unsigned long long*)((t & 1) ? h0B : h0A) + abase)   // h0(t)
                : ((const unsigned long long*)((t & 1) ? h1A : h1B) + abase);  // h1(t-1)
            f32x4 acc[4][4];
#pragma unroll
            for (int i = 0; i < 4; i++)
#pragma unroll
                for (int j = 0; j < 4; j++) acc[i][j] = (f32x4){0.f, 0.f, 0.f, 0.f};
#pragma unroll
            for (int kk = 0; kk < 8; kk++) {
                short8 bl[4];
                if (wv < 4) {
                    bl[0] = *(const short8*)(wpl + 0 * 16 * 2064 + kk * 64);
                    bl[1] = *(const short8*)(wpl + 1 * 16 * 2064 + kk * 64);
                    bl[2] = wreg[0 * 8 + kk];
                    bl[3] = wreg[1 * 8 + kk];
                } else {
                    bl[0] = *(const short8*)(wpl + kk * 64);
                    bl[1] = wreg[0 * 8 + kk];
                    bl[2] = wreg[1 * 8 + kk];
                    bl[3] = wreg[2 * 8 + kk];
                }
#pragma unroll
                for (int rt = 0; rt < 4; rt++) {
                    union AV { unsigned long long u[2]; short8 s; } av;
                    av.u[0] = ald(ap + (size_t)rt * 4096 + kk * 8);
                    av.u[1] = ald(ap + (size_t)rt * 4096 + kk * 8 + 1);
                    acc[rt][0] = __builtin_amdgcn_mfma_f32_16x16x32_bf16(av.s, bl[0], acc[rt][0], 0, 0, 0);
                    acc[rt][1] = __builtin_amdgcn_mfma_f32_16x16x32_bf16(av.s, bl[1], acc[rt][1], 0, 0, 0);
                    acc[rt][2] = __builtin_amdgcn_mfma_f32_16x16x32_bf16(av.s, bl[2], acc[rt][2], 0, 0, 0);
                    acc[rt][3] = __builtin_amdgcn_mfma_f32_16x16x32_bf16(av.s, bl[3], acc[rt][3], 0, 0, 0);
                }
            }

            // 3-stage reduce of 8 partials
            if (wv >= 5) {
                float* P = (wv == 5) ? P0 : (wv == 6) ? P1 : P2;
#pragma unroll
                for (int rt = 0; rt < 4; rt++)
#pragma unroll
                    for (int j = 0; j < 4; j++)
#pragma unroll
                        for (int v = 0; v < 4; v++)
                            P[(rt * 16 + lq * 4 + v) * 68 + j * 16 + lr] = acc[rt][j][v];
            }
            __syncthreads();
            if (wv >= 2 && wv <= 4) {
                float* P = (wv == 2) ? P0 : (wv == 3) ? P1 : P2;
#pragma unroll
                for (int rt = 0; rt < 4; rt++)
#pragma unroll
                    for (int j = 0; j < 4; j++)
#pragma unroll
                        for (int v = 0; v < 4; v++)
                            P[(rt * 16 + lq * 4 + v) * 68 + j * 16 + lr] += acc[rt][j][v];
            }
            __syncthreads();
            if (wv < 2) {
                float* P = (wv == 0) ? P0 : P1;
#pragma unroll
                for (int rt = 0; rt < 4; rt++)
#pragma unroll
                    for (int j = 0; j < 4; j++)
#pragma unroll
                        for (int v = 0; v < 4; v++)
                            P[(rt * 16 + lq * 4 + v) * 68 + j * 16 + lr] += acc[rt][j][v];
            }
            __syncthreads();

            // epilogue: all 512 threads, 2 cells each
            float h0v, h1v;
            {
                const float* pa = P0 + er2 * 68 + up * 8;
                const float* pb = P1 + er2 * 68 + up * 8;
                const float* pc = P2 + er2 * 68 + up * 8;
                float p0 = pa[0] + pb[0] + pc[0] + bsA.x;
                float p1 = pa[1] + pb[1] + pc[1] + bsA.y;
                float p2 = pa[2] + pb[2] + pc[2] + bsA.z;
                float p3 = pa[3] + pb[3] + pc[3] + bsA.w;
                float q0 = pa[4] + pb[4] + pc[4] + bsB.x;
                float q1 = pa[5] + pb[5] + pc[5] + bsB.y;
                float q2 = pa[6] + pb[6] + pc[6] + bsB.z;
                float q3 = pa[7] + pb[7] + pc[7] + bsB.w;
                float i0 = sigm(p0), f0 = sigm(p1), gv0 = tanhf(p2), o0 = sigm(p3);
                float i1 = sigm(q0), f1 = sigm(q1), gv1 = tanhf(q2), o1 = sigm(q3);
                c2.x = f0 * c2.x + i0 * gv0;
                c2.y = f1 * c2.y + i1 * gv1;
                h0v = o0 * tanhf(c2.x);
                h1v = o1 * tanhf(c2.y);
                unsigned hp = (unsigned)f2b(h0v) | ((unsigned)f2b(h1v) << 16);
                unsigned* hout = (t & 1) ? h1B : h1A;
                __hip_atomic_store(hout + (size_t)b1 * 512 + n * 8 + up, hp,
                                   __ATOMIC_RELAXED, __HIP_MEMORY_SCOPE_AGENT);
            }
            __syncthreads();   // drain h stores before signal
            if (tid == 0)
                __hip_atomic_store(fmine, (unsigned)(t + 1),
                                   __ATOMIC_RELAXED, __HIP_MEMORY_SCOPE_AGENT);

            // off-critical-path output stores
            *(float2*)(out + ((size_t)b1 * 256 + t) * 1024 + u0) = make_float2(h0v, h1v);
            if (t == 255) {
                *(float2*)(out + (size_t)128 * 256 * 1024 + (size_t)b1 * 1024 + u0) =
                    make_float2(h0v, h1v);
                *(float2*)(out + (size_t)128 * 256 * 1024 + (size_t)128 * 1024 + (size_t)b1 * 1024 + u0) =
                    make_float2(c2.x, c2.y);
            }
        }
        *(float2*)(c1buf + (size_t)b1 * 1024 + u0) = c2;
    }
}

// ---------------- host ----------------

extern "C" void kernel_launch(void* const* d_in, const int* in_sizes, int n_in,
                              void* d_out, int out_size, void* d_ws, size_t ws_size,
                              hipStream_t stream) {
    const float* x    = (const float*)d_in[0];
    const float* hx0  = (const float*)d_in[1];
    const float* cx0  = (const float*)d_in[2];
    const float* Wih0 = (const float*)d_in[3];
    const float* Whh0 = (const float*)d_in[4];
    const float* bih0 = (const float*)d_in[5];
    const float* bhh0 = (const float*)d_in[6];
    const float* Wih1 = (const float*)d_in[7];
    const float* Whh1 = (const float*)d_in[8];
    const float* bih1 = (const float*)d_in[9];
    const float* bhh1 = (const float*)d_in[10];
    float* out = (float*)d_out;

    const int B = 128, T = 256, I = 256, H = 1024, G4 = 4096;
    const unsigned SMEM_BYTES = 48 * 2064 + 3 * 64 * 68 * 4;  // 99072 + 52224 = 151296

    hipFuncSetAttribute((const void*)&k_fused, hipFuncAttributeMaxDynamicSharedMemorySize, SMEM_BYTES);

    char* p = (char*)d_ws;
    auto alloc = [&](size_t bytes) { char* r = p; p += (bytes + 255) & ~(size_t)255; return r; };
    unsigned short* xbf   = (unsigned short*)alloc((size_t)B * T * I * 2);
    unsigned short* Wih0p = (unsigned short*)alloc((size_t)G4 * I * 2);
    unsigned short* Whh0p = (unsigned short*)alloc((size_t)G4 * H * 2);
    unsigned short* Wih1p = (unsigned short*)alloc((size_t)G4 * H * 2);
    unsigned short* Whh1p = (unsigned short*)alloc((size_t)G4 * H * 2);
    float* bias0 = (float*)alloc(G4 * 4);
    float* bias1 = (float*)alloc(G4 * 4);
    unsigned* hA0 = (unsigned*)alloc((size_t)B * 512 * 4);
    unsigned* hB0 = (unsigned*)alloc((size_t)B * 512 * 4);
    unsigned* hA1 = (unsigned*)alloc((size_t)B * 512 * 4);
    unsigned* hB1 = (unsigned*)alloc((size_t)B * 512 * 4);
    float* c0 = (float*)alloc((size_t)B * H * 4);
    float* c1 = (float*)alloc((size_t)B * H * 4);
    unsigned* flags = (unsigned*)alloc((size_t)256 * 16 * 4);
    size_t fixed = (size_t)(p - (char*)d_ws);
    int TC = 256;
    while (TC > 1 && fixed + (size_t)B * TC * G4 * 2 + 256 > ws_size) TC >>= 1;
    unsigned short* xg = (unsigned short*)alloc((size_t)B * TC * G4 * 2);

    // converts + flag reset (flags carry absolute t+1, monotone within a run)
    hipMemsetAsync(flags, 0, (size_t)256 * 16 * 4, stream);
    k_f2b<<<(B * T * I / 4 + 255) / 256, 256, 0, stream>>>(x, xbf, B * T * I / 4);
    k_perm<<<(G4 * (I / 4) + 255) / 256, 256, 0, stream>>>(Wih0, Wih0p, I / 4);
    k_perm<<<(G4 * (H / 4) + 255) / 256, 256, 0, stream>>>(Whh0, Whh0p, H / 4);
    k_perm<<<(G4 * (H / 4) + 255) / 256, 256, 0, stream>>>(Wih1, Wih1p, H / 4);
    k_perm<<<(G4 * (H / 4) + 255) / 256, 256, 0, stream>>>(Whh1, Whh1p, H / 4);
    k_bias<<<16, 256, 0, stream>>>(bih0, bhh0, bih1, bhh1, bias0, bias1);
    k_init<<<256, 256, 0, stream>>>(hx0, cx0, hB0, hB1, c0, c1);

    for (int t0 = 0; t0 < T; t0 += TC) {
        k_gemm<<<dim3(TC, 32), 256, 0, stream>>>(xbf, Wih0p, xg, I, t0, TC);
        int t0v = t0, TCv = TC;
        const unsigned short* wh0 = Whh0p;
        const unsigned short* wi1 = Wih1p;
        const unsigned short* wh1 = Whh1p;
        const unsigned short* xgp = xg;
        const float* b0p = bias0;
        const float* b1p = bias1;
        float* c0p = c0; float* c1p = c1;
        unsigned* h0a = hA0; unsigned* h0b = hB0;
        unsigned* h1a = hA1; unsigned* h1b = hB1;
        float* op = out;
        unsigned* fl = flags;
        void* args[] = {&wh0, &wi1, &wh1, &xgp, &b0p, &b1p, &c0p, &c1p,
                        &h0a, &h0b, &h1a, &h1b, &op, &fl, &t0v, &TCv};
        hipLaunchCooperativeKernel((const void*)&k_fused, dim3(256), dim3(512), args, SMEM_BYTES, stream);
    }
}

// Round 13
// 3311.472 us; speedup vs baseline: 1.5081x; 1.5081x over previous
//
#include <hip/hip_runtime.h>

typedef __attribute__((ext_vector_type(8))) short short8;
typedef __attribute__((ext_vector_type(4))) float f32x4;

#define DEV static __device__ __forceinline__

DEV unsigned short f2b(float f) {
    union { float f; unsigned u; } v; v.f = f;
    unsigned r = (v.u + 0x7FFFu + ((v.u >> 16) & 1u)) >> 16;
    return (unsigned short)r;
}
DEV float b2f(unsigned short s) {
    union { unsigned u; float f; } v; v.u = ((unsigned)s) << 16;
    return v.f;
}
DEV float sigm(float x) { return 1.0f / (1.0f + __expf(-x)); }

// ---------------- converts ----------------

__global__ void k_f2b(const float* __restrict__ src, unsigned short* __restrict__ dst, int n4) {
    int i = blockIdx.x * blockDim.x + threadIdx.x;
    if (i < n4) {
        float4 v = ((const float4*)src)[i];
        ushort4 o;
        o.x = f2b(v.x); o.y = f2b(v.y); o.z = f2b(v.z); o.w = f2b(v.w);
        ((ushort4*)dst)[i] = o;
    }
}

// dst[(4j+g)][k] = bf16(src[(g*1024+j)][k]); Kq = K/4
__global__ void k_perm(const float* __restrict__ src, unsigned short* __restrict__ dst, int Kq) {
    int i = blockIdx.x * blockDim.x + threadIdx.x;
    int total = 4096 * Kq;
    if (i >= total) return;
    int rp = i / Kq, kq = i - rp * Kq;
    int j = rp >> 2, g = rp & 3;
    float4 v = ((const float4*)src)[(size_t)(g * 1024 + j) * Kq + kq];
    ushort4 o;
    o.x = f2b(v.x); o.y = f2b(v.y); o.z = f2b(v.z); o.w = f2b(v.w);
    ((ushort4*)dst)[(size_t)rp * Kq + kq] = o;
}

__global__ void k_bias(const float* __restrict__ bi0, const float* __restrict__ bh0,
                       const float* __restrict__ bi1, const float* __restrict__ bh1,
                       float* __restrict__ d0, float* __restrict__ d1) {
    int i = blockIdx.x * blockDim.x + threadIdx.x;
    if (i < 4096) {
        int j = i >> 2, g = i & 3, s = g * 1024 + j;
        d0[i] = bi0[s] + bh0[s];
        d1[i] = bi1[s] + bh1[s];
    }
}

// writes initial h (packed 2xbf16) into parity-1 buffers; c as fp32
__global__ void k_init(const float* __restrict__ hx, const float* __restrict__ cx,
                       unsigned* __restrict__ hB0, unsigned* __restrict__ hB1,
                       float* __restrict__ c0, float* __restrict__ c1) {
    int i = blockIdx.x * blockDim.x + threadIdx.x;
    if (i < 128 * 512) {
        int b = i >> 9, j = i & 511;
        const float* p0 = hx + (size_t)b * 1024 + j * 2;
        const float* p1 = hx + 131072 + (size_t)b * 1024 + j * 2;
        hB0[i] = (unsigned)f2b(p0[0]) | ((unsigned)f2b(p0[1]) << 16);
        hB1[i] = (unsigned)f2b(p1[0]) | ((unsigned)f2b(p1[1]) << 16);
        c0[i * 2] = cx[i * 2];
        c0[i * 2 + 1] = cx[i * 2 + 1];
        c1[i * 2] = cx[131072 + i * 2];
        c1[i * 2 + 1] = cx[131072 + i * 2 + 1];
    }
}

// ---------------- persistent recurrent kernel (r10 structure + fused input proj) ----------------
// 256 wgs (1/CU), 512 threads (8 waves). 8 groups x 32 wgs.
// wg = (g: 16 batch rows) x (nb: 128 gate cols). Waves: 8-way split-K over H=1024
// (hh part, 4 atomic-load->MFMA iters, r4/r9/r10-proven shape) PLUS fused input
// projection: per tick, extra MFMAs against register-resident W_ih fragments with
// PLAIN loads of xin (L0: xbf [B][T][256], written by k_f2b; L1: y0 h0-history
// [B][T][1024], written by the completed L0 kernel — kernel-boundary visibility).
// KI = input width (256 / 1024); XI = KI/256 iters per wave (1 / 4).
// W_hh: gate-cols 0..63 in LDS (pitch 2064B), 64..127 in regs (wreg[16] = 64 VGPR).
// W_ih: all in regs (wregi[8*XI]; L0 +32 VGPR, L1 +128 VGPR).
// 3-stage split-K reduce; epilogue waves 0-3, bias only (no xg add).
// Flags: per-wg, 64B stride, absolute tag t+1, lane-parallel poll + __all (r10).
template<int LAYER, int KI, int XI>
__global__ __launch_bounds__(512, 2) void k_lstm(
    const unsigned short* __restrict__ Wh,     // [4096][1024] bf16 gate-interleaved
    const unsigned short* __restrict__ Wi,     // [4096][KI] bf16 gate-interleaved
    const unsigned short* __restrict__ xin,    // [B][T][KI] bf16
    const float* __restrict__ bias,            // [4096]
    float* __restrict__ cbuf,                  // [128*1024] fp32
    unsigned* __restrict__ hA,                 // parity-0 h (packed 2xbf16) [128][512]
    unsigned* __restrict__ hB,                 // parity-1 h
    unsigned short* __restrict__ y0,           // layer0: h history out (null for L1)
    float* __restrict__ out,                   // layer1 only
    unsigned* __restrict__ flags)              // 8 groups x 32 wgs, stride 16 u32 (64B)
{
    extern __shared__ char smem[];
    char* ldsW = smem;                              // 64 rows x 2064 B
    float* P0 = (float*)(smem + 64 * 2064);         // [16][132]
    float* P1 = P0 + 16 * 132;
    float* P2 = P1 + 16 * 132;

    const int tid = threadIdx.x;
    const int g  = (int)blockIdx.x >> 5;   // 0..7: batch rows g*16..+16
    const int nb = (int)blockIdx.x & 31;   // 0..31: gate cols nb*128..+128
    const int wv = tid >> 6;               // wave 0..7 = K eighth
    const int l  = tid & 63;
    const int lr = l & 15, lq = l >> 4;

    // stage LDS W_hh: gate-cols nb*128..+64, 64 rows x 2048B at pitch 2064B
    {
        const char* src = (const char*)(Wh + (size_t)nb * 128 * 1024);
#pragma unroll
        for (int it = 0; it < 16; it++) {
            int idx = it * 512 + tid;
            int row = idx >> 7, inr = (idx & 127) << 4;
            *(uint4*)(ldsW + row * 2064 + inr) = *(const uint4*)(src + (size_t)row * 2048 + inr);
        }
    }
    // reg W_hh: gate-cols nb*128+64..+128, this wave's K-eighth. 16 x short8 = 64 VGPR.
    short8 wreg[16];
    {
        const unsigned short* src = Wh + (size_t)(nb * 128 + 64) * 1024 + wv * 128;
#pragma unroll
        for (int ct = 0; ct < 4; ct++)
#pragma unroll
            for (int kk = 0; kk < 4; kk++)
                wreg[ct * 4 + kk] =
                    *(const short8*)(src + (size_t)(ct * 16 + lr) * 1024 + kk * 32 + lq * 8);
    }
    // reg W_ih: all 8 gate-tiles, this wave's KI-eighth. 8*XI x short8.
    short8 wregi[8 * XI];
    {
#pragma unroll
        for (int j = 0; j < 8; j++)
#pragma unroll
            for (int kk = 0; kk < XI; kk++)
                wregi[j * XI + kk] = *(const short8*)(
                    Wi + (size_t)(nb * 128 + j * 16 + lr) * KI + wv * (KI / 8) + kk * 32 + lq * 8);
    }

    // epilogue fixed mapping (waves 0-3 only): thread -> (row er, 8 gates = 2 units)
    const int er = tid >> 4, ep = tid & 15;   // valid for tid < 256
    const int eb = g * 16 + (er & 15);
    const int ec0 = nb * 128 + ep * 8;
    const int eu0 = nb * 32 + ep * 2;
    float2 c2 = make_float2(0.f, 0.f);
    float4 bsA = make_float4(0.f, 0.f, 0.f, 0.f);
    float4 bsB = make_float4(0.f, 0.f, 0.f, 0.f);
    if (tid < 256) {
        c2 = *(const float2*)(cbuf + (size_t)eb * 1024 + eu0);
        bsA = *(const float4*)(bias + ec0);
        bsB = *(const float4*)(bias + ec0 + 4);
    }

    // mfma A addressing (hh): row g*16+lr, k = wv*128 + kk*32 + lq*8 (u64 units)
    const size_t abase = (size_t)(g * 16 + lr) * 256 + (size_t)wv * 32 + lq * 2;
    const char* wp = ldsW + (size_t)lr * 2064 + wv * 256 + lq * 16;
    // x addressing: row g*16+lr, per-tick base advances by KI elems
    const unsigned short* xrow = xin + (size_t)(g * 16 + lr) * 256 * KI + wv * (KI / 8) + lq * 8;

    const unsigned* fp = flags + (size_t)(g * 32 + (l & 31)) * 16;
    unsigned* fmine = flags + (size_t)(g * 32 + nb) * 16;

    __syncthreads();

    for (int t = 0; t < 256; t++) {
        if (t > 0) {
            const unsigned tgt = (unsigned)t;
            while (!__all(__hip_atomic_load(fp, __ATOMIC_RELAXED,
                                            __HIP_MEMORY_SCOPE_AGENT) >= tgt)) {}
        }

        const unsigned long long* ap =
            (const unsigned long long*)((t & 1) ? hA : hB) + abase;
        f32x4 acc[8];
#pragma unroll
        for (int i = 0; i < 8; i++) acc[i] = (f32x4){0.f, 0.f, 0.f, 0.f};
#pragma unroll
        for (int kk = 0; kk < 4; kk++) {
            union { unsigned long long u[2]; short8 s; } av;
            av.u[0] = __hip_atomic_load(ap + kk * 8,     __ATOMIC_RELAXED, __HIP_MEMORY_SCOPE_AGENT);
            av.u[1] = __hip_atomic_load(ap + kk * 8 + 1, __ATOMIC_RELAXED, __HIP_MEMORY_SCOPE_AGENT);
#pragma unroll
            for (int ct = 0; ct < 4; ct++) {
                short8 b = *(const short8*)(wp + (size_t)ct * 16 * 2064 + kk * 64);
                acc[ct] = __builtin_amdgcn_mfma_f32_16x16x32_bf16(av.s, b, acc[ct], 0, 0, 0);
            }
#pragma unroll
            for (int ct = 0; ct < 4; ct++)
                acc[4 + ct] = __builtin_amdgcn_mfma_f32_16x16x32_bf16(av.s, wreg[ct * 4 + kk], acc[4 + ct], 0, 0, 0);
        }
        // fused input projection: plain loads (xin stable across this kernel)
        {
            const unsigned short* xt = xrow + (size_t)t * KI;
#pragma unroll
            for (int kk = 0; kk < XI; kk++) {
                short8 ax = *(const short8*)(xt + kk * 32);
#pragma unroll
                for (int j = 0; j < 8; j++)
                    acc[j] = __builtin_amdgcn_mfma_f32_16x16x32_bf16(ax, wregi[j * XI + kk], acc[j], 0, 0, 0);
            }
        }

        // 3-stage split-K reduce of 8 partials into P0+P1+P2
        if (wv >= 5) {
            float* P = (wv == 5) ? P0 : (wv == 6) ? P1 : P2;
#pragma unroll
            for (int i = 0; i < 8; i++)
#pragma unroll
                for (int v = 0; v < 4; v++)
                    P[(lq * 4 + v) * 132 + i * 16 + lr] = acc[i][v];
        }
        __syncthreads();
        if (wv >= 2 && wv <= 4) {
            float* P = (wv == 2) ? P0 : (wv == 3) ? P1 : P2;
#pragma unroll
            for (int i = 0; i < 8; i++)
#pragma unroll
                for (int v = 0; v < 4; v++)
                    P[(lq * 4 + v) * 132 + i * 16 + lr] += acc[i][v];
        }
        __syncthreads();
        if (wv < 2) {
            float* P = (wv == 0) ? P0 : P1;
#pragma unroll
            for (int i = 0; i < 8; i++)
#pragma unroll
                for (int v = 0; v < 4; v++)
                    P[(lq * 4 + v) * 132 + i * 16 + lr] += acc[i][v];
        }
        __syncthreads();

        // epilogue (waves 0-3): sum 3 partials + bias; cell update; h store
        float h0v = 0.f, h1v = 0.f;
        if (tid < 256) {
            const float* pa = P0 + er * 132 + ep * 8;
            const float* pb = P1 + er * 132 + ep * 8;
            const float* pc = P2 + er * 132 + ep * 8;
            float p0 = pa[0] + pb[0] + pc[0] + bsA.x;
            float p1 = pa[1] + pb[1] + pc[1] + bsA.y;
            float p2 = pa[2] + pb[2] + pc[2] + bsA.z;
            float p3 = pa[3] + pb[3] + pc[3] + bsA.w;
            float q0 = pa[4] + pb[4] + pc[4] + bsB.x;
            float q1 = pa[5] + pb[5] + pc[5] + bsB.y;
            float q2 = pa[6] + pb[6] + pc[6] + bsB.z;
            float q3 = pa[7] + pb[7] + pc[7] + bsB.w;
            float i0 = sigm(p0), f0 = sigm(p1), gv0 = tanhf(p2), o0 = sigm(p3);
            float i1 = sigm(q0), f1 = sigm(q1), gv1 = tanhf(q2), o1 = sigm(q3);
            c2.x = f0 * c2.x + i0 * gv0;
            c2.y = f1 * c2.y + i1 * gv1;
            h0v = o0 * tanhf(c2.x);
            h1v = o1 * tanhf(c2.y);
            unsigned hp = (unsigned)f2b(h0v) | ((unsigned)f2b(h1v) << 16);
            unsigned* hout = (t & 1) ? hB : hA;
            __hip_atomic_store(hout + (size_t)eb * 512 + eu0 / 2, hp,
                               __ATOMIC_RELAXED, __HIP_MEMORY_SCOPE_AGENT);
        }
        __syncthreads();   // drains waves 0-3's h stores before signal
        if (tid == 0)
            __hip_atomic_store(fmine, (unsigned)(t + 1),
                               __ATOMIC_RELAXED, __HIP_MEMORY_SCOPE_AGENT);

        // off-critical-path stores AFTER signal
        if (tid < 256) {
            if (LAYER == 0) {
                unsigned hp = (unsigned)f2b(h0v) | ((unsigned)f2b(h1v) << 16);
                ((unsigned*)y0)[((size_t)eb * 256 + t) * 512 + eu0 / 2] = hp;
            } else {
                *(float2*)(out + ((size_t)eb * 256 + t) * 1024 + eu0) = make_float2(h0v, h1v);
                if (t == 255) {
                    *(float2*)(out + (size_t)128 * 256 * 1024 + (size_t)eb * 1024 + eu0) =
                        make_float2(h0v, h1v);
                    *(float2*)(out + (size_t)128 * 256 * 1024 + (size_t)128 * 1024 + (size_t)eb * 1024 + eu0) =
                        make_float2(c2.x, c2.y);
                }
            }
        }
    }
    if (tid < 256)
        *(float2*)(cbuf + (size_t)eb * 1024 + eu0) = c2;
}

// ---------------- host ----------------

extern "C" void kernel_launch(void* const* d_in, const int* in_sizes, int n_in,
                              void* d_out, int out_size, void* d_ws, size_t ws_size,
                              hipStream_t stream) {
    const float* x    = (const float*)d_in[0];
    const float* hx0  = (const float*)d_in[1];
    const float* cx0  = (const float*)d_in[2];
    const float* Wih0 = (const float*)d_in[3];
    const float* Whh0 = (const float*)d_in[4];
    const float* bih0 = (const float*)d_in[5];
    const float* bhh0 = (const float*)d_in[6];
    const float* Wih1 = (const float*)d_in[7];
    const float* Whh1 = (const float*)d_in[8];
    const float* bih1 = (const float*)d_in[9];
    const float* bhh1 = (const float*)d_in[10];
    float* out = (float*)d_out;

    const int B = 128, T = 256, I = 256, H = 1024, G4 = 4096;
    const unsigned SMEM_BYTES = 64 * 2064 + 3 * 16 * 132 * 4;  // 157440
    const int FLAGS_U32 = 8 * 32 * 16;  // per layer

    hipFuncSetAttribute((const void*)&k_lstm<0, 256, 1>, hipFuncAttributeMaxDynamicSharedMemorySize, SMEM_BYTES);
    hipFuncSetAttribute((const void*)&k_lstm<1, 1024, 4>, hipFuncAttributeMaxDynamicSharedMemorySize, SMEM_BYTES);

    char* p = (char*)d_ws;
    auto alloc = [&](size_t bytes) { char* r = p; p += (bytes + 255) & ~(size_t)255; return r; };
    unsigned short* xbf   = (unsigned short*)alloc((size_t)B * T * I * 2);
    unsigned short* Wih0p = (unsigned short*)alloc((size_t)G4 * I * 2);
    unsigned short* Whh0p = (unsigned short*)alloc((size_t)G4 * H * 2);
    unsigned short* Wih1p = (unsigned short*)alloc((size_t)G4 * H * 2);
    unsigned short* Whh1p = (unsigned short*)alloc((size_t)G4 * H * 2);
    float* bias0 = (float*)alloc(G4 * 4);
    float* bias1 = (float*)alloc(G4 * 4);
    unsigned short* y0 = (unsigned short*)alloc((size_t)B * T * H * 2);
    unsigned* hA0 = (unsigned*)alloc((size_t)B * 512 * 4);
    unsigned* hB0 = (unsigned*)alloc((size_t)B * 512 * 4);
    unsigned* hA1 = (unsigned*)alloc((size_t)B * 512 * 4);
    unsigned* hB1 = (unsigned*)alloc((size_t)B * 512 * 4);
    float* c0 = (float*)alloc((size_t)B * H * 4);
    float* c1 = (float*)alloc((size_t)B * H * 4);
    unsigned* flags0 = (unsigned*)alloc((size_t)2 * FLAGS_U32 * 4);
    unsigned* flags1 = flags0 + FLAGS_U32;

    // converts + flag reset (flags carry absolute t+1, monotone within a launch)
    hipMemsetAsync(flags0, 0, (size_t)2 * FLAGS_U32 * 4, stream);
    k_f2b<<<(B * T * I / 4 + 255) / 256, 256, 0, stream>>>(x, xbf, B * T * I / 4);
    k_perm<<<(G4 * (I / 4) + 255) / 256, 256, 0, stream>>>(Wih0, Wih0p, I / 4);
    k_perm<<<(G4 * (H / 4) + 255) / 256, 256, 0, stream>>>(Whh0, Whh0p, H / 4);
    k_perm<<<(G4 * (H / 4) + 255) / 256, 256, 0, stream>>>(Wih1, Wih1p, H / 4);
    k_perm<<<(G4 * (H / 4) + 255) / 256, 256, 0, stream>>>(Whh1, Whh1p, H / 4);
    k_bias<<<16, 256, 0, stream>>>(bih0, bhh0, bih1, bhh1, bias0, bias1);
    k_init<<<256, 256, 0, stream>>>(hx0, cx0, hB0, hB1, c0, c1);

    // ---- layer 0 (fused input projection from xbf, KI=256) ----
    {
        const unsigned short* Whp = Whh0p;
        const unsigned short* Wip = Wih0p;
        const unsigned short* xp = xbf;
        const float* bp = bias0;
        float* cp = c0;
        unsigned* ha = hA0; unsigned* hb = hB0;
        unsigned short* y0p = y0;
        float* op = nullptr;
        unsigned* fl = flags0;
        void* args[] = {&Whp, &Wip, &xp, &bp, &cp, &ha, &hb, &y0p, &op, &fl};
        hipLaunchCooperativeKernel((const void*)&k_lstm<0, 256, 1>, dim3(256), dim3(512), args, SMEM_BYTES, stream);
    }
    // ---- layer 1 (fused input projection from y0, KI=1024) ----
    {
        const unsigned short* Whp = Whh1p;
        const unsigned short* Wip = Wih1p;
        const unsigned short* xp = y0;
        const float* bp = bias1;
        float* cp = c1;
        unsigned* ha = hA1; unsigned* hb = hB1;
        unsigned short* y0p = nullptr;
        float* op = out;
        unsigned* fl = flags1;
        void* args[] = {&Whp, &Wip, &xp, &bp, &cp, &ha, &hb, &y0p, &op, &fl};
        hipLaunchCooperativeKernel((const void*)&k_lstm<1, 1024, 4>, dim3(256), dim3(512), args, SMEM_BYTES, stream);
    }
}